// Round 5
// baseline (1727.968 us; speedup 1.0000x reference)
//
#include <hip/hip_runtime.h>

constexpr int kB = 128;
constexpr int kT = 1024;
constexpr int kI = 64;
constexpr int kH = 512;
constexpr int kO = 32;
constexpr float kTau = 0.2f;
constexpr float kNoise = 0.05f;

__device__ __forceinline__ float fast_tanh(float x) {
    // tanh(x) = 1 - 2/(e^{2x}+1); exact limits at +-inf, ~1e-7 abs error.
    float e = __expf(2.0f * x);
    return 1.0f - 2.0f * __builtin_amdgcn_rcpf(e + 1.0f);
}

// One DPP-add reduction stage (VALU pipe, no LDS).
template <int CTRL, int RMASK>
__device__ __forceinline__ float dpp_add(float s) {
    return s + __int_as_float(__builtin_amdgcn_update_dpp(
        0, __float_as_int(s), CTRL, RMASK, 0xf, true));
}

// ---------------------------------------------------------------------------
// inp_kernel: traj[b][t][h] = kTau*(u[b,t,:]·Win_w[h,:] + Win_b[h])
//                           + kNoise*noise[t][b][h]
// One h per thread (512 threads) so the tau-scaled Win row is only 64 VGPRs
// — cannot spill (the 2-h/thread variant risked 128-float scratch spill =
// ~4.3 GB hidden HBM traffic). u rows are block-uniform -> SMEM (SGPRs).
// 2048 blocks x 512 thr = 16 waves/CU.
// ---------------------------------------------------------------------------
constexpr int ROWS_PB = 64;

__global__ __launch_bounds__(512, 2) void inp_kernel(
    const float* __restrict__ u, const float* __restrict__ Win_w,
    const float* __restrict__ Win_b, const float* __restrict__ noise,
    float* __restrict__ traj)
{
    const int h = threadIdx.x;
    const size_t row0 = (size_t)blockIdx.x * ROWS_PB;

    float W[kI];
    #pragma unroll
    for (int i = 0; i < kI; i += 4) {
        float4 w = *(const float4*)&Win_w[(size_t)h * kI + i];
        W[i] = w.x * kTau; W[i + 1] = w.y * kTau;
        W[i + 2] = w.z * kTau; W[i + 3] = w.w * kTau;
    }
    const float twb = Win_b[h] * kTau;

    for (int r = 0; r < ROWS_PB; ++r) {
        const size_t row = row0 + r;
        const int t  = (int)(row & (kT - 1));
        const int bb = (int)(row >> 10);
        float nz = noise[((size_t)t * kB + bb) * kH + h];   // issue early
        const float* ur = u + row * kI;                     // uniform -> SMEM
        float ip = twb;
        #pragma unroll
        for (int i = 0; i < kI; ++i) ip = fmaf(ur[i], W[i], ip);
        traj[row * kH + h] = fmaf(kNoise, nz, ip);
    }
}

// ---------------------------------------------------------------------------
// scan_kernel: ONE WAVE per batch row (64 threads), 8 h per thread
// (h = lane + 64k). Per step, entirely in-wave, ZERO barriers / LDS:
//   - 8 tanh; 6 accumulators built by 8-deep per-thread FMA (48 FMA)
//   - 6 interleaved 6-stage DPP butterflies -> totals in lane 63
//   - v_readlane(63) -> 6 uniform scalars in SGPRs
//   - per h: rec = 4-FMA chain seeded with the precomputed c (input proj +
//     noise, folded in traj by inp_kernel); x = fma(0.8, x, rec)
//   - 8 coalesced stores; c prefetched distance 2 (vmcnt never drained —
//     no barriers exist to drain it).
// Chain ~550 cyc/step vs ~1250 for the 8-wave 2-barrier version.
// ---------------------------------------------------------------------------
__global__ __launch_bounds__(64) void scan_kernel(
    const float* __restrict__ x0, const float* __restrict__ M_rnn,
    const float* __restrict__ N_rnn, const float* __restrict__ L_tb,
    const float* __restrict__ M_tb, const float* __restrict__ N_tb,
    float* __restrict__ traj, float* __restrict__ xfin)
{
    const int b    = blockIdx.x;
    const int lane = threadIdx.x;            // single wave: 0..63

    const float sr = kTau / (float)kH;
    const float st = kTau / ((float)kH * (float)kH);

    float Nr0[8], Nr1[8], Mt0[8], Mt1[8], Nt0[8], Nt1[8];
    float tMr0[8], tMr1[8], tLt0[8], tLt1[8];
    float x[8];

    #pragma unroll
    for (int k = 0; k < 8; ++k) {
        const int h = lane + 64 * k;
        float2 v;
        v = *(const float2*)&N_rnn[2 * h]; Nr0[k] = v.x;      Nr1[k] = v.y;
        v = *(const float2*)&M_tb[2 * h];  Mt0[k] = v.x;      Mt1[k] = v.y;
        v = *(const float2*)&N_tb[2 * h];  Nt0[k] = v.x;      Nt1[k] = v.y;
        v = *(const float2*)&M_rnn[2 * h]; tMr0[k] = v.x * sr; tMr1[k] = v.y * sr;
        v = *(const float2*)&L_tb[2 * h];  tLt0[k] = v.x * st; tLt1[k] = v.y * st;
        x[k] = x0[b * kH + h];
    }

    float* tp = traj + (size_t)b * kT * kH + lane;   // c read / x write

    float cA[8], cB[8];                              // distance-2 prefetch
    #pragma unroll
    for (int k = 0; k < 8; ++k) {
        cA[k] = tp[64 * k];
        cB[k] = tp[kH + 64 * k];
    }

    auto step = [&](int t, float* c) {
        float r[8];
        #pragma unroll
        for (int k = 0; k < 8; ++k) r[k] = fast_tanh(x[k]);

        float a0 = 0.f, a1 = 0.f, m0 = 0.f, m1 = 0.f, n0 = 0.f, n1 = 0.f;
        #pragma unroll
        for (int k = 0; k < 8; ++k) {
            a0 = fmaf(r[k], Nr0[k], a0);
            a1 = fmaf(r[k], Nr1[k], a1);
            m0 = fmaf(r[k], Mt0[k], m0);
            m1 = fmaf(r[k], Mt1[k], m1);
            n0 = fmaf(r[k], Nt0[k], n0);
            n1 = fmaf(r[k], Nt1[k], n1);
        }
        // 6 interleaved DPP butterflies; totals land in lane 63.
        #define RSTAGE(CTRL, MASK)                                          \
            a0 = dpp_add<CTRL, MASK>(a0); a1 = dpp_add<CTRL, MASK>(a1);     \
            m0 = dpp_add<CTRL, MASK>(m0); m1 = dpp_add<CTRL, MASK>(m1);     \
            n0 = dpp_add<CTRL, MASK>(n0); n1 = dpp_add<CTRL, MASK>(n1);
        RSTAGE(0x111, 0xf)   // row_shr:1
        RSTAGE(0x112, 0xf)   // row_shr:2
        RSTAGE(0x114, 0xf)   // row_shr:4
        RSTAGE(0x118, 0xf)   // row_shr:8
        RSTAGE(0x142, 0xa)   // row_bcast15 -> rows 1,3
        RSTAGE(0x143, 0xc)   // row_bcast31 -> rows 2,3; lane63 = wave total
        #undef RSTAGE

        const float sa0 = __int_as_float(
            __builtin_amdgcn_readlane(__float_as_int(a0), 63));
        const float sa1 = __int_as_float(
            __builtin_amdgcn_readlane(__float_as_int(a1), 63));
        const float sm0 = __int_as_float(
            __builtin_amdgcn_readlane(__float_as_int(m0), 63));
        const float sm1 = __int_as_float(
            __builtin_amdgcn_readlane(__float_as_int(m1), 63));
        const float sn0 = __int_as_float(
            __builtin_amdgcn_readlane(__float_as_int(n0), 63));
        const float sn1 = __int_as_float(
            __builtin_amdgcn_readlane(__float_as_int(n1), 63));
        const float p0 = sm0 * sn0;
        const float p1 = sm1 * sn1;

        #pragma unroll
        for (int k = 0; k < 8; ++k) {
            float rc = fmaf(p1, tLt1[k], c[k]);
            rc = fmaf(p0, tLt0[k], rc);
            rc = fmaf(sa1, tMr1[k], rc);
            rc = fmaf(sa0, tMr0[k], rc);
            x[k] = fmaf(1.0f - kTau, x[k], rc);
            tp[(size_t)t * kH + 64 * k] = x[k];
        }
        // prefetch c for t+2 (tail wraps; value unused after loop ends)
        const int t2 = (t + 2) & (kT - 1);
        #pragma unroll
        for (int k = 0; k < 8; ++k)
            c[k] = tp[(size_t)t2 * kH + 64 * k];
    };

    for (int t = 0; t < kT; t += 2) {
        step(t,     cA);
        step(t + 1, cB);
    }
    #pragma unroll
    for (int k = 0; k < 8; ++k)
        xfin[b * kH + lane + 64 * k] = x[k];
}

// ---------------------------------------------------------------------------
// out_kernel: out[row][o] = sum_h tanh(traj[row][h])*Wout_w[o][h] + Wout_b[o]
// 512 blocks x 256 thr; thread = (rg,og): 4 rows x 8 outputs. NO A-staging:
// the 4 lanes sharing rg issue IDENTICAL traj addresses -> one coalesced
// request (broadcast), so direct global reads carry zero redundant HBM
// traffic. LDS holds only W^T [h][o] (64 KB); inner reads are conflict-free
// float4 (words 0..31 across og). No barriers in the main loop; next
// iteration's 4 loads are register-prefetched under the 128-FMA body.
// ---------------------------------------------------------------------------
__global__ __launch_bounds__(256) void out_kernel(
    const float* __restrict__ traj, const float* __restrict__ Wout_w,
    const float* __restrict__ Wout_b, float* __restrict__ out)
{
    __shared__ float Wl[kH][kO];   // 64 KB, [h][o]
    const int tid = threadIdx.x;
    {
        const int o  = tid >> 3;           // 0..31
        const int cb = (tid & 7) * 64;     // h base
        #pragma unroll
        for (int j = 0; j < 64; j += 4) {
            float4 w = *(const float4*)&Wout_w[(size_t)o * kH + cb + j];
            Wl[cb + j + 0][o] = w.x;
            Wl[cb + j + 1][o] = w.y;
            Wl[cb + j + 2][o] = w.z;
            Wl[cb + j + 3][o] = w.w;
        }
    }
    __syncthreads();

    const int og = tid & 3;                // outputs og*8 .. og*8+7
    const int rg = tid >> 2;               // rows rg*4 .. rg*4+3
    const size_t row0 = (size_t)blockIdx.x * 256 + (size_t)rg * 4;
    const float* tb = traj + row0 * kH;

    float acc[4][8];
    #pragma unroll
    for (int k = 0; k < 4; ++k)
        #pragma unroll
        for (int j = 0; j < 8; ++j) acc[k][j] = 0.f;

    float4 a[4], n[4];
    #pragma unroll
    for (int k = 0; k < 4; ++k) a[k] = *(const float4*)&tb[k * kH];

    for (int hh = 0; hh < kH; hh += 4) {
        const int hn = hh + 4;
        if (hn < kH) {
            #pragma unroll
            for (int k = 0; k < 4; ++k)
                n[k] = *(const float4*)&tb[k * kH + hn];
        }
        float tv[4][4];
        #pragma unroll
        for (int k = 0; k < 4; ++k) {
            tv[k][0] = fast_tanh(a[k].x);
            tv[k][1] = fast_tanh(a[k].y);
            tv[k][2] = fast_tanh(a[k].z);
            tv[k][3] = fast_tanh(a[k].w);
        }
        #pragma unroll
        for (int j = 0; j < 4; ++j) {
            float4 w0 = *(const float4*)&Wl[hh + j][og * 8];
            float4 w1 = *(const float4*)&Wl[hh + j][og * 8 + 4];
            const float wv[8] = {w0.x, w0.y, w0.z, w0.w,
                                 w1.x, w1.y, w1.z, w1.w};
            #pragma unroll
            for (int k = 0; k < 4; ++k)
                #pragma unroll
                for (int jj = 0; jj < 8; ++jj)
                    acc[k][jj] = fmaf(tv[k][j], wv[jj], acc[k][jj]);
        }
        #pragma unroll
        for (int k = 0; k < 4; ++k) a[k] = n[k];
    }

    #pragma unroll
    for (int k = 0; k < 4; ++k) {
        const size_t row = row0 + k;
        float4 v0, v1;
        v0.x = acc[k][0] + Wout_b[og * 8 + 0];
        v0.y = acc[k][1] + Wout_b[og * 8 + 1];
        v0.z = acc[k][2] + Wout_b[og * 8 + 2];
        v0.w = acc[k][3] + Wout_b[og * 8 + 3];
        v1.x = acc[k][4] + Wout_b[og * 8 + 4];
        v1.y = acc[k][5] + Wout_b[og * 8 + 5];
        v1.z = acc[k][6] + Wout_b[og * 8 + 6];
        v1.w = acc[k][7] + Wout_b[og * 8 + 7];
        *(float4*)&out[row * kO + og * 8]     = v0;
        *(float4*)&out[row * kO + og * 8 + 4] = v1;
    }
}

extern "C" void kernel_launch(void* const* d_in, const int* in_sizes, int n_in,
                              void* d_out, int out_size, void* d_ws, size_t ws_size,
                              hipStream_t stream) {
    const float* u      = (const float*)d_in[0];
    const float* x0     = (const float*)d_in[1];
    const float* noise  = (const float*)d_in[2];
    const float* Win_w  = (const float*)d_in[3];
    const float* Win_b  = (const float*)d_in[4];
    const float* Wout_w = (const float*)d_in[5];
    const float* Wout_b = (const float*)d_in[6];
    const float* M_rnn  = (const float*)d_in[7];
    const float* N_rnn  = (const float*)d_in[8];
    const float* L_tb   = (const float*)d_in[9];
    const float* M_tb   = (const float*)d_in[10];
    const float* N_tb   = (const float*)d_in[11];

    float* out  = (float*)d_out;                       // [B,T,O]
    float* xfin = out + (size_t)kB * kT * kO;          // [B,H]
    float* traj = xfin + (size_t)kB * kH;              // [B,T,H]

    inp_kernel<<<dim3((kB * kT) / ROWS_PB), dim3(512), 0, stream>>>(
        u, Win_w, Win_b, noise, traj);
    scan_kernel<<<dim3(kB), dim3(64), 0, stream>>>(
        x0, M_rnn, N_rnn, L_tb, M_tb, N_tb, traj, xfin);
    out_kernel<<<dim3((kB * kT) / 256), dim3(256), 0, stream>>>(
        traj, Wout_w, Wout_b, out);
}